// Round 4
// baseline (589.454 us; speedup 1.0000x reference)
//
#include <hip/hip_runtime.h>
#include <stdint.h>

// ---------------------------------------------------------------------------
// QuantizedLinear: out[M,N] = x[M,K] @ dequant(Wpacked)[N,K]^T
//   M = 8192, K = 4096, N = 4096
// R4: fused wide prepass (x->bf16, W->bf16) + m97-style 128x128 bf16 MFMA
// GEMM with XOR-swizzled LDS (0 bank conflicts) and nontemporal C stores
// (keep B/A tiles resident in L2/L3 -> shorter vmcnt(0) drain tail).
// ---------------------------------------------------------------------------

typedef short short8 __attribute__((ext_vector_type(8)));   // 8 bf16 = 4 VGPR
typedef float floatx4 __attribute__((ext_vector_type(4)));  // MFMA acc

#define BM 128
#define BN 128
#define BK 32

// round-to-nearest-even fp32 -> bf16 (returned in low 16 bits)
__device__ __forceinline__ uint32_t f2bf(float f) {
  union { float f; uint32_t u; } v; v.f = f;
  return (v.u + 0x7FFFu + ((v.u >> 16) & 1u)) >> 16;
}

// async global->LDS, 16B per lane; LDS dest is wave-uniform base + lane*16
__device__ __forceinline__ void async_copy16(const void* g, void* l) {
  __builtin_amdgcn_global_load_lds(
      (const __attribute__((address_space(1))) uint32_t*)g,
      (__attribute__((address_space(3))) uint32_t*)l, 16, 0, 0);
}

// ----------------- fused prepass: x -> bf16  and  W -> bf16 ----------------
// Blocks [0, xblocks): convert x. 64 B read / 32 B write per thread.
// Blocks [xblocks, ...): dequant W. weight_packed (uint8 in the reference)
// arrives as int32 per element; byte p covers k=2p (HIGH nibble), k=2p+1 (low).
__global__ void prep_kernel(const float4* __restrict__ x, uint4* __restrict__ xb,
                            int xblocks,
                            const int* __restrict__ wp, const float* __restrict__ cent,
                            const float* __restrict__ scales,
                            unsigned short* __restrict__ wb, int K) {
  if ((int)blockIdx.x < xblocks) {
    // ---- x conversion: thread t handles 16 floats -> 16 bf16
    int t = blockIdx.x * blockDim.x + threadIdx.x;
    float4 v0 = x[4 * t + 0];
    float4 v1 = x[4 * t + 1];
    float4 v2 = x[4 * t + 2];
    float4 v3 = x[4 * t + 3];
    uint4 o0, o1;
    o0.x = f2bf(v0.x) | (f2bf(v0.y) << 16);
    o0.y = f2bf(v0.z) | (f2bf(v0.w) << 16);
    o0.z = f2bf(v1.x) | (f2bf(v1.y) << 16);
    o0.w = f2bf(v1.z) | (f2bf(v1.w) << 16);
    o1.x = f2bf(v2.x) | (f2bf(v2.y) << 16);
    o1.y = f2bf(v2.z) | (f2bf(v2.w) << 16);
    o1.z = f2bf(v3.x) | (f2bf(v3.y) << 16);
    o1.w = f2bf(v3.z) | (f2bf(v3.w) << 16);
    xb[2 * t]     = o0;
    xb[2 * t + 1] = o1;
  } else {
    // ---- W dequant: thread u handles 8 packed bytes -> 16 bf16 weights
    __shared__ float lut[16];
    if (threadIdx.x < 16) lut[threadIdx.x] = cent[threadIdx.x];
    __syncthreads();
    int u = (blockIdx.x - xblocks) * blockDim.x + threadIdx.x;
    const int tpr = K >> 4;            // threads per row = 256 (pow2)
    int o = u / tpr;
    int j = u & (tpr - 1);
    const int* base = wp + (size_t)o * (K >> 1) + j * 8;
    const int4 p0 = *(const int4*)(base);
    const int4 p1 = *(const int4*)(base + 4);
    int kbase = j * 16;                // 16 weights, single 64-block
    float s = scales[(size_t)o * (K >> 6) + (kbase >> 6)];
    int pb[8] = {p0.x, p0.y, p0.z, p0.w, p1.x, p1.y, p1.z, p1.w};
    uint32_t w32[8];
#pragma unroll
    for (int i = 0; i < 8; ++i) {
      unsigned b = (unsigned)pb[i] & 0xFFu;
      uint32_t hi = f2bf(lut[b >> 4] * s);   // first element of the byte
      uint32_t lo = f2bf(lut[b & 15] * s);   // second element
      w32[i] = hi | (lo << 16);
    }
    uint4* dst = (uint4*)(wb + (size_t)o * K + kbase);
    dst[0] = make_uint4(w32[0], w32[1], w32[2], w32[3]);
    dst[1] = make_uint4(w32[4], w32[5], w32[6], w32[7]);
  }
}

// ------------------------------ main GEMM ----------------------------------
// A[M,K] bf16, B[N,K] bf16 (B^T layout), C[M,N] fp32.
// LDS swizzle: data (row r, 16B-colblock c) stored at slot r*4 + (c^((r>>1)&3)).
__global__ __launch_bounds__(256) void gemm_bt(const unsigned short* __restrict__ A,
                                               const unsigned short* __restrict__ B,
                                               float* __restrict__ C,
                                               int M, int N, int K) {
  __shared__ unsigned short As[BM * BK];  // 8 KiB
  __shared__ unsigned short Bs[BN * BK];  // 8 KiB
  const int tid   = threadIdx.x;
  const int lane  = tid & 63;
  const int wave  = tid >> 6;
  const int waveM = wave >> 1;   // 2x2 wave grid, each wave does 64x64
  const int waveN = wave & 1;
  const int bm = blockIdx.y * BM;
  const int bn = blockIdx.x * BN;

  // staging: DMA slot = lane*16B. Slot s holds (row=s>>2, cblk=(s&3)^((s>>3)&3))
  const int srow = tid >> 2;
  const int scol = 8 * ((tid & 3) ^ ((tid >> 3) & 3));   // swizzled colblock
  const unsigned short* aptr0 = A + (size_t)(bm + srow) * K + scol;
  const unsigned short* aptr1 = A + (size_t)(bm + 64 + srow) * K + scol;
  const unsigned short* bptr0 = B + (size_t)(bn + srow) * K + scol;
  const unsigned short* bptr1 = B + (size_t)(bn + 64 + srow) * K + scol;
  char* ldsA = (char*)As + wave * 1024;   // wave-uniform LDS bases
  char* ldsB = (char*)Bs + wave * 1024;

  // fragment reads: lane -> row (lane&15), k-colblock (lane>>4), XOR swizzle
  const int fr  = lane & 15;
  const int fc  = (lane >> 4) ^ ((lane >> 1) & 3);  // swizzled k-block
  const short8* ar[4];
  const short8* br[4];
#pragma unroll
  for (int i = 0; i < 4; ++i) {
    ar[i] = (const short8*)(As + (waveM * 64 + i * 16 + fr) * BK + fc * 8);
    br[i] = (const short8*)(Bs + (waveN * 64 + i * 16 + fr) * BK + fc * 8);
  }

  floatx4 acc[4][4] = {};

  for (int kt = 0; kt < K; kt += BK) {
    __syncthreads();                         // protect LDS from overwrite
    async_copy16(aptr0 + kt, ldsA);
    async_copy16(aptr1 + kt, ldsA + 4096);
    async_copy16(bptr0 + kt, ldsB);
    async_copy16(bptr1 + kt, ldsB + 4096);
    __syncthreads();                         // vmcnt(0)+lgkmcnt(0) drain

    short8 af[4], bw[4];
#pragma unroll
    for (int i = 0; i < 4; ++i) { af[i] = *ar[i]; bw[i] = *br[i]; }
#pragma unroll
    for (int mi = 0; mi < 4; ++mi)
#pragma unroll
      for (int nj = 0; nj < 4; ++nj)
        acc[mi][nj] = __builtin_amdgcn_mfma_f32_16x16x32_bf16(af[mi], bw[nj], acc[mi][nj], 0, 0, 0);
  }

  // C/D layout: col = lane&15, row = (lane>>4)*4 + reg
  // Nontemporal: C is write-once streaming; keep it out of L2/L3 so the
  // A/B staging working set stays resident (drain-tail theory, R4).
  const int r0 = bm + waveM * 64 + (lane >> 4) * 4;
  const int c0 = bn + waveN * 64 + (lane & 15);
#pragma unroll
  for (int mi = 0; mi < 4; ++mi)
#pragma unroll
    for (int nj = 0; nj < 4; ++nj)
#pragma unroll
      for (int i = 0; i < 4; ++i)
        __builtin_nontemporal_store(acc[mi][nj][i],
            &C[(size_t)(r0 + mi * 16 + i) * N + (c0 + nj * 16)]);
}

// ------------------------- fallback (ws too small) -------------------------
__global__ void naive_kernel(const float* __restrict__ x, const int* __restrict__ wp,
                             const float* __restrict__ cent, const float* __restrict__ scales,
                             float* __restrict__ out, int M, int N, int K) {
  __shared__ float lut[16];
  if (threadIdx.x < 16) lut[threadIdx.x] = cent[threadIdx.x];
  __syncthreads();
  int n = blockIdx.x * blockDim.x + threadIdx.x;
  int m = blockIdx.y;
  if (n >= N || m >= M) return;
  const float* xr = x + (size_t)m * K;
  const int* wr = wp + (size_t)n * (K / 2);
  float acc = 0.f;
  for (int kb = 0; kb < K / 64; ++kb) {
    float s = scales[(size_t)n * (K / 64) + kb];
    float a = 0.f;
    for (int j = 0; j < 32; ++j) {
      unsigned b = (unsigned)wr[kb * 32 + j] & 0xFFu;
      a += xr[kb * 64 + 2 * j] * lut[b >> 4] + xr[kb * 64 + 2 * j + 1] * lut[b & 15];
    }
    acc += a * s;
  }
  out[(size_t)m * N + n] = acc;
}

// ------------------------------- launcher ----------------------------------
extern "C" void kernel_launch(void* const* d_in, const int* in_sizes, int n_in,
                              void* d_out, int out_size, void* d_ws, size_t ws_size,
                              hipStream_t stream) {
  const float* x      = (const float*)d_in[0];
  const int*   wp     = (const int*)d_in[1];
  const float* cent   = (const float*)d_in[2];
  const float* scales = (const float*)d_in[3];
  float*       out    = (float*)d_out;

  const int K = 4096;
  const int M = in_sizes[0] / K;                        // 8192
  const int O = (int)(((size_t)in_sizes[1] * 2) / K);   // 4096

  size_t need = (size_t)M * K * 2 + (size_t)O * K * 2;  // 96 MiB
  if (ws_size >= need) {
    unsigned short* xb = (unsigned short*)d_ws;
    unsigned short* wb = xb + (size_t)M * K;

    int xthreads = M * K / 16;                 // 16 floats per thread
    int xblocks  = xthreads / 256;             // 2048
    int wthreads = O * K / 16;                 // 16 weights per thread
    int wblocks  = wthreads / 256;             // 1024
    prep_kernel<<<xblocks + wblocks, 256, 0, stream>>>(
        (const float4*)x, (uint4*)xb, xblocks, wp, cent, scales, wb, K);

    dim3 grid(O / BN, M / BM);  // (32, 64)
    gemm_bt<<<grid, 256, 0, stream>>>(xb, wb, out, M, O, K);
  } else {
    dim3 grid((O + 255) / 256, M);
    naive_kernel<<<grid, 256, 0, stream>>>(x, wp, cent, scales, out, M, O, K);
  }
}

// Round 5
// 517.530 us; speedup vs baseline: 1.1390x; 1.1390x over previous
//
#include <hip/hip_runtime.h>
#include <stdint.h>

// ---------------------------------------------------------------------------
// QuantizedLinear: out[M,N] = x[M,K] @ dequant(Wpacked)[N,K]^T
//   M = 8192, K = 4096, N = 4096
// R5: prepass (unchanged) + 128x128 GEMM restructured to BK=64 with
// mfma_f32_32x32x16_bf16 (half the barriers of BK=32, half the MFMA issue
// count), XOR-8 LDS swizzle (conflict-free), nontemporal C stores.
// ---------------------------------------------------------------------------

typedef short short8  __attribute__((ext_vector_type(8)));    // 8 bf16 = 4 VGPR
typedef float floatx16 __attribute__((ext_vector_type(16)));  // 32x32 MFMA acc

#define BM 128
#define BN 128
#define BK 64

// round-to-nearest-even fp32 -> bf16 (returned in low 16 bits)
__device__ __forceinline__ uint32_t f2bf(float f) {
  union { float f; uint32_t u; } v; v.f = f;
  return (v.u + 0x7FFFu + ((v.u >> 16) & 1u)) >> 16;
}

// async global->LDS, 16B per lane; LDS dest is wave-uniform base + lane*16
__device__ __forceinline__ void async_copy16(const void* g, void* l) {
  __builtin_amdgcn_global_load_lds(
      (const __attribute__((address_space(1))) uint32_t*)g,
      (__attribute__((address_space(3))) uint32_t*)l, 16, 0, 0);
}

// ----------------- fused prepass: x -> bf16  and  W -> bf16 ----------------
__global__ void prep_kernel(const float4* __restrict__ x, uint4* __restrict__ xb,
                            int xblocks,
                            const int* __restrict__ wp, const float* __restrict__ cent,
                            const float* __restrict__ scales,
                            unsigned short* __restrict__ wb, int K) {
  if ((int)blockIdx.x < xblocks) {
    int t = blockIdx.x * blockDim.x + threadIdx.x;
    float4 v0 = x[4 * t + 0];
    float4 v1 = x[4 * t + 1];
    float4 v2 = x[4 * t + 2];
    float4 v3 = x[4 * t + 3];
    uint4 o0, o1;
    o0.x = f2bf(v0.x) | (f2bf(v0.y) << 16);
    o0.y = f2bf(v0.z) | (f2bf(v0.w) << 16);
    o0.z = f2bf(v1.x) | (f2bf(v1.y) << 16);
    o0.w = f2bf(v1.z) | (f2bf(v1.w) << 16);
    o1.x = f2bf(v2.x) | (f2bf(v2.y) << 16);
    o1.y = f2bf(v2.z) | (f2bf(v2.w) << 16);
    o1.z = f2bf(v3.x) | (f2bf(v3.y) << 16);
    o1.w = f2bf(v3.z) | (f2bf(v3.w) << 16);
    xb[2 * t]     = o0;
    xb[2 * t + 1] = o1;
  } else {
    __shared__ float lut[16];
    if (threadIdx.x < 16) lut[threadIdx.x] = cent[threadIdx.x];
    __syncthreads();
    int u = (blockIdx.x - xblocks) * blockDim.x + threadIdx.x;
    const int tpr = K >> 4;            // threads per row = 256 (pow2)
    int o = u / tpr;
    int j = u & (tpr - 1);
    const int* base = wp + (size_t)o * (K >> 1) + j * 8;
    const int4 p0 = *(const int4*)(base);
    const int4 p1 = *(const int4*)(base + 4);
    int kbase = j * 16;                // 16 weights, single 64-block
    float s = scales[(size_t)o * (K >> 6) + (kbase >> 6)];
    int pb[8] = {p0.x, p0.y, p0.z, p0.w, p1.x, p1.y, p1.z, p1.w};
    uint32_t w32[8];
#pragma unroll
    for (int i = 0; i < 8; ++i) {
      unsigned b = (unsigned)pb[i] & 0xFFu;
      uint32_t hi = f2bf(lut[b >> 4] * s);   // first element of the byte
      uint32_t lo = f2bf(lut[b & 15] * s);   // second element
      w32[i] = hi | (lo << 16);
    }
    uint4* dst = (uint4*)(wb + (size_t)o * K + kbase);
    dst[0] = make_uint4(w32[0], w32[1], w32[2], w32[3]);
    dst[1] = make_uint4(w32[4], w32[5], w32[6], w32[7]);
  }
}

// ------------------------------ main GEMM ----------------------------------
// A[M,K] bf16, B[N,K] bf16 (B^T layout), C[M,N] fp32.
// BK=64: row = 8 x 16B-blocks. Data (row r, blk c) stored at slot
// r*8 + (c ^ (r&7)). Staging lane l (per 1KiB copy of 8 rows): row=l>>3,
// loads global blk (l&7)^((l>>3)&7). Fragment reads XOR the same r&7.
__global__ __launch_bounds__(256) void gemm_bt(const unsigned short* __restrict__ A,
                                               const unsigned short* __restrict__ B,
                                               float* __restrict__ C,
                                               int M, int N, int K) {
  __shared__ unsigned short As[BM * BK];  // 16 KiB
  __shared__ unsigned short Bs[BN * BK];  // 16 KiB
  const int tid   = threadIdx.x;
  const int lane  = tid & 63;
  const int wave  = tid >> 6;
  const int waveM = wave >> 1;   // 2x2 wave grid, each wave does 64x64
  const int waveN = wave & 1;
  const int bm = blockIdx.y * BM;
  const int bn = blockIdx.x * BN;

  // ---- staging: wave w stages A rows [w*32, w*32+32) and same B rows,
  // as 4 copies of 1 KiB (8 rows x 128 B). Lane l -> row l>>3, swizzled blk.
  const int srow = lane >> 3;                       // 0..7 within copy
  const int sblk = (lane & 7) ^ srow;               // swizzled 16B-block
  const unsigned short* gA[4];
  const unsigned short* gB[4];
#pragma unroll
  for (int c = 0; c < 4; ++c) {
    int row = wave * 32 + c * 8 + srow;
    gA[c] = A + (size_t)(bm + row) * K + sblk * 8;
    gB[c] = B + (size_t)(bn + row) * K + sblk * 8;
  }
  char* ldsA = (char*)As + wave * 4096;   // wave-uniform LDS bases
  char* ldsB = (char*)Bs + wave * 4096;

  // ---- fragments: 32x32x16 MFMA. Lane: row/col = lane&31, k-group = lane>>5.
  const int lr = lane & 31;
  const int g  = lane >> 5;
  const int e  = lr & 7;                 // swizzle term (rows: (mi*32+lr)&7 = lr&7)
  const int baseA0 = (waveM * 64 + lr) * BK;        // shorts
  const int baseA1 = baseA0 + 32 * BK;
  const int baseB0 = (waveN * 64 + lr) * BK;
  const int baseB1 = baseB0 + 32 * BK;
  // physical 16B-block offset (in shorts) per k-step, loop-invariant
  int pb[4];
#pragma unroll
  for (int s = 0; s < 4; ++s) pb[s] = (((s << 1) | g) ^ e) << 3;

  floatx16 acc00 = {}, acc01 = {}, acc10 = {}, acc11 = {};

  for (int kt = 0; kt < K; kt += BK) {
    __syncthreads();                         // protect LDS from overwrite
#pragma unroll
    for (int c = 0; c < 4; ++c) {
      async_copy16(gA[c] + kt, ldsA + c * 1024);
      async_copy16(gB[c] + kt, ldsB + c * 1024);
    }
    __syncthreads();                         // vmcnt(0)+lgkmcnt(0) drain

#pragma unroll
    for (int s = 0; s < 4; ++s) {
      short8 a0 = *(const short8*)(As + baseA0 + pb[s]);
      short8 a1 = *(const short8*)(As + baseA1 + pb[s]);
      short8 b0 = *(const short8*)(Bs + baseB0 + pb[s]);
      short8 b1 = *(const short8*)(Bs + baseB1 + pb[s]);
      acc00 = __builtin_amdgcn_mfma_f32_32x32x16_bf16(a0, b0, acc00, 0, 0, 0);
      acc01 = __builtin_amdgcn_mfma_f32_32x32x16_bf16(a0, b1, acc01, 0, 0, 0);
      acc10 = __builtin_amdgcn_mfma_f32_32x32x16_bf16(a1, b0, acc10, 0, 0, 0);
      acc11 = __builtin_amdgcn_mfma_f32_32x32x16_bf16(a1, b1, acc11, 0, 0, 0);
    }
  }

  // C/D 32x32 layout (m74/m101): col = lane&31, row = (reg&3)+8*(reg>>2)+4*(lane>>5)
  const int colb = bn + waveN * 64 + lr;
  const int rowb = bm + waveM * 64 + 4 * g;
  const floatx16* accs[4] = {&acc00, &acc01, &acc10, &acc11};
#pragma unroll
  for (int mi = 0; mi < 2; ++mi)
#pragma unroll
    for (int nj = 0; nj < 2; ++nj) {
      const floatx16 a = *accs[mi * 2 + nj];
      const int col = colb + nj * 32;
      const int rb  = rowb + mi * 32;
#pragma unroll
      for (int reg = 0; reg < 16; ++reg) {
        int row = rb + (reg & 3) + 8 * (reg >> 2);
        __builtin_nontemporal_store(a[reg], &C[(size_t)row * N + col]);
      }
    }
}

// ------------------------- fallback (ws too small) -------------------------
__global__ void naive_kernel(const float* __restrict__ x, const int* __restrict__ wp,
                             const float* __restrict__ cent, const float* __restrict__ scales,
                             float* __restrict__ out, int M, int N, int K) {
  __shared__ float lut[16];
  if (threadIdx.x < 16) lut[threadIdx.x] = cent[threadIdx.x];
  __syncthreads();
  int n = blockIdx.x * blockDim.x + threadIdx.x;
  int m = blockIdx.y;
  if (n >= N || m >= M) return;
  const float* xr = x + (size_t)m * K;
  const int* wr = wp + (size_t)n * (K / 2);
  float acc = 0.f;
  for (int kb = 0; kb < K / 64; ++kb) {
    float s = scales[(size_t)n * (K / 64) + kb];
    float a = 0.f;
    for (int j = 0; j < 32; ++j) {
      unsigned b = (unsigned)wr[kb * 32 + j] & 0xFFu;
      a += xr[kb * 64 + 2 * j] * lut[b >> 4] + xr[kb * 64 + 2 * j + 1] * lut[b & 15];
    }
    acc += a * s;
  }
  out[(size_t)m * N + n] = acc;
}

// ------------------------------- launcher ----------------------------------
extern "C" void kernel_launch(void* const* d_in, const int* in_sizes, int n_in,
                              void* d_out, int out_size, void* d_ws, size_t ws_size,
                              hipStream_t stream) {
  const float* x      = (const float*)d_in[0];
  const int*   wp     = (const int*)d_in[1];
  const float* cent   = (const float*)d_in[2];
  const float* scales = (const float*)d_in[3];
  float*       out    = (float*)d_out;

  const int K = 4096;
  const int M = in_sizes[0] / K;                        // 8192
  const int O = (int)(((size_t)in_sizes[1] * 2) / K);   // 4096

  size_t need = (size_t)M * K * 2 + (size_t)O * K * 2;  // 96 MiB
  if (ws_size >= need) {
    unsigned short* xb = (unsigned short*)d_ws;
    unsigned short* wb = xb + (size_t)M * K;

    int xthreads = M * K / 16;                 // 16 floats per thread
    int xblocks  = xthreads / 256;             // 2048
    int wthreads = O * K / 16;                 // 16 weights per thread
    int wblocks  = wthreads / 256;             // 1024
    prep_kernel<<<xblocks + wblocks, 256, 0, stream>>>(
        (const float4*)x, (uint4*)xb, xblocks, wp, cent, scales, wb, K);

    dim3 grid(O / BN, M / BM);  // (32, 64)
    gemm_bt<<<grid, 256, 0, stream>>>(xb, wb, out, M, O, K);
  } else {
    dim3 grid((O + 255) / 256, M);
    naive_kernel<<<grid, 256, 0, stream>>>(x, wp, cent, scales, out, M, O, K);
  }
}